// Round 17
// baseline (1012.391 us; speedup 1.0000x reference)
//
#include <hip/hip_runtime.h>
#include <hip/hip_fp16.h>

#define NNODES 100000
#define NEDGES 3200000
#define NGRAPH 4096
#define SBCNT 196         // super-buckets: dst>>9 (512 nodes each)
#define SBCAP 17504       // per-SB capacity: mean 16327 + 9 sigma
#define P1CHUNK 4096
#define P1CAP 56          // LDS bin capacity: mean 20.9 + 7.7 sigma
#define P1GRID 782        // ceil(E / P1CHUNK)
#define AGG_GRID 2048     // exactly 8 blocks/CU on 256 CUs
#define BN_EPS 1e-5f
#define INV_N (1.0f / 100000.0f)

// ---------------- zero helper: two disjoint regions in one dispatch ----------
__global__ void k_zero2(int* __restrict__ a, int na, int* __restrict__ b, int nb) {
  int i = blockIdx.x * blockDim.x + threadIdx.x;
  int st = gridDim.x * blockDim.x;
  for (int j = i; j < na; j += st) a[j] = 0;
  for (int j = i; j < nb; j += st) b[j] = 0;
}

// ---------------- pass 1: LDS-binned partition into 196 super-buckets ----------
__global__ void k_part1(const int* __restrict__ src, const int* __restrict__ dst,
                        int* __restrict__ sbcur, int* __restrict__ sbbuf, int e) {
  __shared__ int cnt[SBCNT];
  __shared__ int base[SBCNT];
  __shared__ int bins[SBCNT * P1CAP];
  int t = threadIdx.x;
  int start = blockIdx.x * P1CHUNK;
  int end = min(start + P1CHUNK, e);
  for (int i = t; i < SBCNT; i += 256) cnt[i] = 0;
  __syncthreads();
  for (int i = start + t; i < end; i += 256) {
    int s = src[i], d = dst[i];
    int sb = d >> 9;
    int en = (s << 9) | (d & 511);
    int pos = atomicAdd(&cnt[sb], 1);
    if (pos < P1CAP) {
      bins[sb * P1CAP + pos] = en;
    } else {  // rare overflow: direct global append (correctness preserved)
      int gp = atomicAdd(&sbcur[sb], 1);
      if (gp < SBCAP) sbbuf[(size_t)sb * SBCAP + gp] = en;
    }
  }
  __syncthreads();
  if (t < SBCNT) {
    int c = min(cnt[t], P1CAP);
    base[t] = (c > 0) ? atomicAdd(&sbcur[t], c) : 0;
  }
  __syncthreads();
  int lane = t & 63, wid = t >> 6;
  for (int b = wid; b < SBCNT; b += 4) {
    int c = min(cnt[b], P1CAP);
    if (lane < c) {
      int gp = base[b] + lane;
      if (gp < SBCAP) sbbuf[(size_t)b * SBCAP + gp] = bins[b * P1CAP + lane];
    }
  }
}

// ---------------- pass 2: single-writer CSR build per super-bucket + dinv ------
__global__ void k_part2(const int* __restrict__ sbcur, const int* __restrict__ sbbuf,
                        int* __restrict__ slots, int* __restrict__ deg,
                        int* __restrict__ rowstart, float* __restrict__ dinv) {
  __shared__ int cnt[512];
  __shared__ int pfx[512];
  __shared__ int cur[512];
  int sb = blockIdx.x;
  int t = threadIdx.x;
  int n = min(sbcur[sb], SBCAP);
  const int* __restrict__ pb = sbbuf + (size_t)sb * SBCAP;
  cnt[t] = 0;
  __syncthreads();
  for (int i = t; i < n; i += 512) atomicAdd(&cnt[pb[i] & 511], 1);
  __syncthreads();
  int myc = cnt[t];
  pfx[t] = myc;
  __syncthreads();
  for (int o = 1; o < 512; o <<= 1) {
    int x = (t >= o) ? pfx[t - o] : 0;
    __syncthreads();
    pfx[t] += x;
    __syncthreads();
  }
  int excl = pfx[t] - myc;
  int node = sb * 512 + t;
  if (node < NNODES) {
    deg[node] = myc;
    rowstart[node] = sb * SBCAP + excl;
    dinv[node] = rsqrtf((float)myc + 1.0f);
  }
  cur[t] = 0;
  __syncthreads();
  pfx[t] = excl;
  __syncthreads();
  for (int i = t; i < n; i += 512) {
    int e = pb[i];
    int dl = e & 511;
    int pos = atomicAdd(&cur[dl], 1);
    slots[(size_t)sb * SBCAP + pfx[dl] + pos] = e >> 9;
  }
}

// ---------------- [n,64] x [64,64] GEMM: k-outer, 16 accs, fp16 I/O ------------
// PRO: 0 = none, 1 = BN+relu on A, 2 = BN+relu+residual on A
// A_HALF: A (and res) are fp16; staging converts to f32 in LDS.
// EPI_DINV: scale row by dinv[row].  EPI_BR: bias + relu (proj layer).
// Output C is always fp16.
template <int PRO, bool A_HALF, bool EPI_DINV, bool EPI_BR>
__global__ void k_gemm64(const void* __restrict__ Ain, const float* __restrict__ W,
                         const float* __restrict__ bias, const float* __restrict__ stats,
                         const float* __restrict__ g, const float* __restrict__ bb,
                         const __half* __restrict__ res, const float* __restrict__ dinv,
                         __half* __restrict__ C, int n) {
  __shared__ float Ws[64 * 64];    // [k][c] row-major
  __shared__ float As[64 * 64];    // [r][k] contiguous
  __shared__ float scs[64], shs[64], bs[64];
  int t = threadIdx.x;
  {
    const float4* W4 = (const float4*)W;
    float4* Ws4 = (float4*)Ws;
    for (int i = t; i < 1024; i += 256) Ws4[i] = W4[i];
  }
  if (t < 64) {
    if (EPI_BR) bs[t] = bias[t];
    if (PRO >= 1) {
      float mu = stats[t] * INV_N;
      float var = stats[64 + t] * INV_N - mu * mu;
      float sc = g[t] * rsqrtf(var + BN_EPS);
      scs[t] = sc;
      shs[t] = bb[t] - mu * sc;
    }
  }
  int row0 = blockIdx.x * 64;
  int rows = min(64, n - row0);
  __syncthreads();
  if constexpr (A_HALF) {
    const __half2* A2 = (const __half2*)((const __half*)Ain + (size_t)row0 * 64);
    const __half2* R2 = (PRO == 2) ? (const __half2*)(res + (size_t)row0 * 64) : nullptr;
    for (int i = t; i < rows * 32; i += 256) {
      float2 f = __half22float2(A2[i]);
      int r = i >> 5;
      int c0 = (i & 31) * 2;
      if (PRO >= 1) {
        f.x = fmaxf(fmaf(f.x, scs[c0], shs[c0]), 0.0f);
        f.y = fmaxf(fmaf(f.y, scs[c0 + 1], shs[c0 + 1]), 0.0f);
        if (PRO == 2) {
          float2 r2 = __half22float2(R2[i]);
          f.x += r2.x;
          f.y += r2.y;
        }
      }
      As[r * 64 + c0] = f.x;
      As[r * 64 + c0 + 1] = f.y;
    }
  } else {
    const float4* A4 = (const float4*)((const float*)Ain + (size_t)row0 * 64);
    float4* As4 = (float4*)As;
    for (int i = t; i < rows * 16; i += 256) As4[i] = A4[i];
  }
  __syncthreads();
  int c = t & 63;
  int w = t >> 6;
  float acc[16];
#pragma unroll
  for (int j = 0; j < 16; ++j) acc[j] = 0.0f;
#pragma unroll 4
  for (int k = 0; k < 64; ++k) {
    float wv = Ws[(k << 6) + c];
#pragma unroll
    for (int j = 0; j < 16; ++j) {
      acc[j] = fmaf(As[((w + 4 * j) << 6) + k], wv, acc[j]);
    }
  }
#pragma unroll
  for (int j = 0; j < 16; ++j) {
    int r = w + 4 * j;
    if (r < rows) {
      float o = acc[j];
      if (EPI_BR) o = fmaxf(o + bs[c], 0.0f);
      if (EPI_DINV) o *= dinv[row0 + r];
      C[(size_t)(row0 + r) * 64 + c] = __float2half(o);
    }
  }
}

// ---------------- aggregate: wave/node; scalar CSR index loads; fp16 gather ----
// 24-deep gather ILP; next-node deg/rowstart/dinv prefetch; fused last-block
// stats reduction (threadfence + ticket) replaces the k_stats_reduce dispatch.
__global__ __launch_bounds__(256, 8)
void k_agg(const int* __restrict__ deg, const int* __restrict__ rowstart,
           const int* __restrict__ slots, const __half* __restrict__ y,
           const float* __restrict__ dinv, __half* __restrict__ ag,
           float* __restrict__ pstats, float* __restrict__ stats,
           int* __restrict__ ticket) {
  int t = threadIdx.x;
  int lane = t & 63, wid = t >> 6;
  int wave = blockIdx.x * 4 + wid;
  int nw = gridDim.x * 4;
  float s = 0.0f, q = 0.0f;
  int node0 = wave;
  int pm = 0, prs = 0;
  float pdv = 0.0f;
  if (node0 < NNODES) {
    int nn = __builtin_amdgcn_readfirstlane(node0);
    pm = deg[nn];
    prs = rowstart[nn];
    pdv = dinv[nn];
  }
  for (; node0 < NNODES; node0 += nw) {
    int m = pm;
    int rs = prs;
    float dv = pdv;
    int nxt = node0 + nw;
    if (nxt < NNODES) {  // prefetch next node's scalars (hides s_load latency)
      int nn = __builtin_amdgcn_readfirstlane(nxt);
      pm = deg[nn];
      prs = rowstart[nn];
      pdv = dinv[nn];
    }
    const int* __restrict__ sp = slots + rs;
    float a0 = __half2float(y[(size_t)node0 * 64 + lane]);  // self-loop term
    float a1 = 0.0f, a2 = 0.0f, a3 = 0.0f;
    float a4 = 0.0f, a5 = 0.0f, a6 = 0.0f, a7 = 0.0f;
    int k = 0;
    for (; k + 24 <= m; k += 24) {
      int i00 = sp[k + 0],  i01 = sp[k + 1],  i02 = sp[k + 2],  i03 = sp[k + 3];
      int i04 = sp[k + 4],  i05 = sp[k + 5],  i06 = sp[k + 6],  i07 = sp[k + 7];
      int i08 = sp[k + 8],  i09 = sp[k + 9],  i10 = sp[k + 10], i11 = sp[k + 11];
      int i12 = sp[k + 12], i13 = sp[k + 13], i14 = sp[k + 14], i15 = sp[k + 15];
      int i16 = sp[k + 16], i17 = sp[k + 17], i18 = sp[k + 18], i19 = sp[k + 19];
      int i20 = sp[k + 20], i21 = sp[k + 21], i22 = sp[k + 22], i23 = sp[k + 23];
      __half v00 = y[(size_t)i00 * 64 + lane];
      __half v01 = y[(size_t)i01 * 64 + lane];
      __half v02 = y[(size_t)i02 * 64 + lane];
      __half v03 = y[(size_t)i03 * 64 + lane];
      __half v04 = y[(size_t)i04 * 64 + lane];
      __half v05 = y[(size_t)i05 * 64 + lane];
      __half v06 = y[(size_t)i06 * 64 + lane];
      __half v07 = y[(size_t)i07 * 64 + lane];
      __half v08 = y[(size_t)i08 * 64 + lane];
      __half v09 = y[(size_t)i09 * 64 + lane];
      __half v10 = y[(size_t)i10 * 64 + lane];
      __half v11 = y[(size_t)i11 * 64 + lane];
      __half v12 = y[(size_t)i12 * 64 + lane];
      __half v13 = y[(size_t)i13 * 64 + lane];
      __half v14 = y[(size_t)i14 * 64 + lane];
      __half v15 = y[(size_t)i15 * 64 + lane];
      __half v16 = y[(size_t)i16 * 64 + lane];
      __half v17 = y[(size_t)i17 * 64 + lane];
      __half v18 = y[(size_t)i18 * 64 + lane];
      __half v19 = y[(size_t)i19 * 64 + lane];
      __half v20 = y[(size_t)i20 * 64 + lane];
      __half v21 = y[(size_t)i21 * 64 + lane];
      __half v22 = y[(size_t)i22 * 64 + lane];
      __half v23 = y[(size_t)i23 * 64 + lane];
      a0 += __half2float(v00); a1 += __half2float(v01);
      a2 += __half2float(v02); a3 += __half2float(v03);
      a4 += __half2float(v04); a5 += __half2float(v05);
      a6 += __half2float(v06); a7 += __half2float(v07);
      a0 += __half2float(v08); a1 += __half2float(v09);
      a2 += __half2float(v10); a3 += __half2float(v11);
      a4 += __half2float(v12); a5 += __half2float(v13);
      a6 += __half2float(v14); a7 += __half2float(v15);
      a0 += __half2float(v16); a1 += __half2float(v17);
      a2 += __half2float(v18); a3 += __half2float(v19);
      a4 += __half2float(v20); a5 += __half2float(v21);
      a6 += __half2float(v22); a7 += __half2float(v23);
    }
    for (; k + 8 <= m; k += 8) {
      int i0 = sp[k + 0], i1 = sp[k + 1], i2 = sp[k + 2], i3 = sp[k + 3];
      int i4 = sp[k + 4], i5 = sp[k + 5], i6 = sp[k + 6], i7 = sp[k + 7];
      __half v0 = y[(size_t)i0 * 64 + lane];
      __half v1 = y[(size_t)i1 * 64 + lane];
      __half v2 = y[(size_t)i2 * 64 + lane];
      __half v3 = y[(size_t)i3 * 64 + lane];
      __half v4 = y[(size_t)i4 * 64 + lane];
      __half v5 = y[(size_t)i5 * 64 + lane];
      __half v6 = y[(size_t)i6 * 64 + lane];
      __half v7 = y[(size_t)i7 * 64 + lane];
      a0 += __half2float(v0); a1 += __half2float(v1);
      a2 += __half2float(v2); a3 += __half2float(v3);
      a4 += __half2float(v4); a5 += __half2float(v5);
      a6 += __half2float(v6); a7 += __half2float(v7);
    }
    for (; k + 4 <= m; k += 4) {
      int i0 = sp[k + 0], i1 = sp[k + 1], i2 = sp[k + 2], i3 = sp[k + 3];
      __half v0 = y[(size_t)i0 * 64 + lane];
      __half v1 = y[(size_t)i1 * 64 + lane];
      __half v2 = y[(size_t)i2 * 64 + lane];
      __half v3 = y[(size_t)i3 * 64 + lane];
      a0 += __half2float(v0); a1 += __half2float(v1);
      a2 += __half2float(v2); a3 += __half2float(v3);
    }
    for (; k < m; ++k) a0 += __half2float(y[(size_t)sp[k] * 64 + lane]);
    float o = dv * (((a0 + a1) + (a2 + a3)) + ((a4 + a5) + (a6 + a7)));
    ag[(size_t)node0 * 64 + lane] = __float2half(o);
    s += o;
    q = fmaf(o, o, q);
  }
  __shared__ float ls[256], lq[256];
  __shared__ int isLast;
  ls[t] = s;
  lq[t] = q;
  __syncthreads();
  if (t < 64) {
    pstats[blockIdx.x * 128 + t] = ls[t] + ls[64 + t] + ls[128 + t] + ls[192 + t];
    pstats[blockIdx.x * 128 + 64 + t] = lq[t] + lq[64 + t] + lq[128 + t] + lq[192 + t];
  }
  // last-block global stats reduction (threadFenceReduction pattern)
  __threadfence();
  __syncthreads();
  if (t == 0) isLast = (atomicAdd(ticket, 1) == (int)gridDim.x - 1) ? 1 : 0;
  __syncthreads();
  if (isLast) {
    __threadfence();
    if (t < 128) {
      float S0 = 0, S1 = 0, S2 = 0, S3 = 0, S4 = 0, S5 = 0, S6 = 0, S7 = 0;
      for (int i = 0; i < AGG_GRID; i += 8) {
        S0 += pstats[(size_t)(i + 0) * 128 + t];
        S1 += pstats[(size_t)(i + 1) * 128 + t];
        S2 += pstats[(size_t)(i + 2) * 128 + t];
        S3 += pstats[(size_t)(i + 3) * 128 + t];
        S4 += pstats[(size_t)(i + 4) * 128 + t];
        S5 += pstats[(size_t)(i + 5) * 128 + t];
        S6 += pstats[(size_t)(i + 6) * 128 + t];
        S7 += pstats[(size_t)(i + 7) * 128 + t];
      }
      stats[t] = ((S0 + S1) + (S2 + S3)) + ((S4 + S5) + (S6 + S7));
    }
  }
}

// ---------------- pool: run-length accumulate over sorted batch, fused BN3+relu ----
__global__ void k_pool(const __half* __restrict__ ag, const float* __restrict__ stats,
                       const float* __restrict__ g, const float* __restrict__ bb,
                       const int* __restrict__ batch, float* __restrict__ psum,
                       float* __restrict__ pcnt) {
  int t = threadIdx.x, lane = t & 63;
  int wave = blockIdx.x * 4 + (t >> 6);
  int c0 = wave * 32;
  if (c0 >= NNODES) return;
  float mu = stats[lane] * INV_N;
  float var = stats[64 + lane] * INV_N - mu * mu;
  float sc = g[lane] * rsqrtf(var + BN_EPS);
  float sh = bb[lane] - mu * sc;
  int gprev = -1;
  float av = 0.0f, cv = 0.0f;
  int end = min(c0 + 32, NNODES);
  for (int node = c0; node < end; ++node) {
    int gi = batch[node];
    if (gi != gprev) {
      if (gprev >= 0) {
        atomicAdd(&psum[gprev * 64 + lane], av);
        if (lane == 0) atomicAdd(&pcnt[gprev], cv);
      }
      gprev = gi;
      av = 0.0f;
      cv = 0.0f;
    }
    av += fmaxf(fmaf(__half2float(ag[(size_t)node * 64 + lane]), sc, sh), 0.0f);
    cv += 1.0f;
  }
  if (gprev >= 0) {
    atomicAdd(&psum[gprev * 64 + lane], av);
    if (lane == 0) atomicAdd(&pcnt[gprev], cv);
  }
}

// ---------------- head MLP ----------------
__global__ void k_head(const float* __restrict__ psum, const float* __restrict__ pcnt,
                       const float* __restrict__ W1, const float* __restrict__ b1,
                       const float* __restrict__ W2, const float* __restrict__ b2,
                       float* __restrict__ out) {
  int gidx = blockIdx.x;
  int t = threadIdx.x;
  __shared__ float pooled[64];
  __shared__ float hid[32];
  float cnt = fmaxf(pcnt[gidx], 1.0f);
  pooled[t] = psum[gidx * 64 + t] / cnt;
  __syncthreads();
  if (t < 32) {
    float a = b1[t];
#pragma unroll
    for (int k = 0; k < 64; ++k) a = fmaf(pooled[k], W1[k * 32 + t], a);
    hid[t] = fmaxf(a, 0.0f);
  }
  __syncthreads();
  if (t == 0) {
    float o = b2[0];
#pragma unroll
    for (int j = 0; j < 32; ++j) o = fmaf(hid[j], W2[j], o);
    out[gidx] = o;
  }
}

extern "C" void kernel_launch(void* const* d_in, const int* in_sizes, int n_in,
                              void* d_out, int out_size, void* d_ws, size_t ws_size,
                              hipStream_t stream) {
  const float* x       = (const float*)d_in[0];
  const int*   eidx    = (const int*)d_in[1];
  const int*   batch   = (const int*)d_in[2];
  const float* proj_W  = (const float*)d_in[3];
  const float* proj_b  = (const float*)d_in[4];
  const float* conv1_W = (const float*)d_in[5];
  const float* conv2_W = (const float*)d_in[7];
  const float* conv3_W = (const float*)d_in[9];
  const float* bn1_g   = (const float*)d_in[11];
  const float* bn1_b   = (const float*)d_in[12];
  const float* bn2_g   = (const float*)d_in[13];
  const float* bn2_b   = (const float*)d_in[14];
  const float* bn3_g   = (const float*)d_in[15];
  const float* bn3_b   = (const float*)d_in[16];
  const float* head_W1 = (const float*)d_in[17];
  const float* head_b1 = (const float*)d_in[18];
  const float* head_W2 = (const float*)d_in[19];
  const float* head_b2 = (const float*)d_in[20];
  float* out = (float*)d_out;

  const int N = NNODES, E = NEDGES, G = NGRAPH;
  const int* src = eidx;
  const int* dst = eidx + E;

  char* p = (char*)d_ws;
  auto align256 = [](size_t v) { return (v + 255) & ~(size_t)255; };
  int* sbcur = (int*)p;       p += align256((size_t)SBCNT * 4);
  int* deg = (int*)p;         p += align256((size_t)N * 4);
  int* rowstart = (int*)p;    p += align256((size_t)N * 4);
  int* slots = (int*)p;       p += align256((size_t)SBCNT * SBCAP * 4);  // 13.7 MB CSR
  float* dinv = (float*)p;    p += align256((size_t)N * 4);
  __half* x016 = (__half*)p;  p += align256((size_t)N * 64 * 2);  // 12.8 MB
  __half* y16 = (__half*)p;   p += align256((size_t)N * 64 * 2);  // 12.8 MB
  __half* ag16 = (__half*)p;  p += align256((size_t)N * 64 * 2);  // 12.8 MB
  float* pstats = (float*)p;  p += align256((size_t)AGG_GRID * 128 * 4);
  float* stats1 = (float*)p;  p += align256(128 * 4);
  float* stats2 = (float*)p;  p += align256(128 * 4);
  float* stats3 = (float*)p;  p += align256(128 * 4);
  float* psum = (float*)p;    p += align256((size_t)G * 64 * 4);
  float* pcnt = (float*)p;    p += align256((size_t)G * 4);
  int* tick = (int*)p;        p += align256(64 * 4);   // 3 layer tickets (+pad)
  // sbbuf (13.7 MB) aliases y16+ag16 (25.6 MB): dead before either is written.
  int* sbbuf = (int*)y16;

  const int TB = 256;
  int gemm_grid = (N + 63) / 64;

  // ---- zero: sbcur + (psum | pcnt | tickets) in one dispatch ----
  int zn2 = G * 64 + G + ((int)((char*)tick - (char*)pcnt) - G * 4) / 4 + 64;
  k_zero2<<<(G * 64 + G + 64 + TB - 1) / TB, TB, 0, stream>>>(
      sbcur, SBCNT, (int*)psum, zn2);

  // ---- adjacency build: LDS-binned partition + single-writer CSR (+dinv) ----
  k_part1<<<P1GRID, TB, 0, stream>>>(src, dst, sbcur, sbbuf, E);
  k_part2<<<SBCNT, 512, 0, stream>>>(sbcur, sbbuf, slots, deg, rowstart, dinv);

  // ---- proj: x0 = relu(x @ W + b)  (f32 in, fp16 out) ----
  k_gemm64<0, false, false, true><<<gemm_grid, TB, 0, stream>>>(
      x, proj_W, proj_b, nullptr, nullptr, nullptr, nullptr, nullptr, x016, N);

  // ---- layer 1 (stats fused into agg last block) ----
  k_gemm64<0, true, true, false><<<gemm_grid, TB, 0, stream>>>(
      x016, conv1_W, nullptr, nullptr, nullptr, nullptr, nullptr, dinv, y16, N);
  k_agg<<<AGG_GRID, TB, 0, stream>>>(deg, rowstart, slots, y16, dinv, ag16,
                                     pstats, stats1, tick + 0);

  // ---- layer 2 (BN1+relu fused into A-load) ----
  k_gemm64<1, true, true, false><<<gemm_grid, TB, 0, stream>>>(
      ag16, conv2_W, nullptr, stats1, bn1_g, bn1_b, nullptr, dinv, y16, N);
  k_agg<<<AGG_GRID, TB, 0, stream>>>(deg, rowstart, slots, y16, dinv, ag16,
                                     pstats, stats2, tick + 1);

  // ---- layer 3 (BN2+relu+x0 residual fused into A-load) ----
  k_gemm64<2, true, true, false><<<gemm_grid, TB, 0, stream>>>(
      ag16, conv3_W, nullptr, stats2, bn2_g, bn2_b, x016, dinv, y16, N);
  k_agg<<<AGG_GRID, TB, 0, stream>>>(deg, rowstart, slots, y16, dinv, ag16,
                                     pstats, stats3, tick + 2);

  // ---- pool (BN3+relu fused, run-length over sorted batch) + head ----
  k_pool<<<(N + 127) / 128, TB, 0, stream>>>(ag16, stats3, bn3_g, bn3_b, batch, psum, pcnt);
  k_head<<<G, 64, 0, stream>>>(psum, pcnt, head_W1, head_b1, head_W2, head_b2, out);
}

// Round 18
// 395.332 us; speedup vs baseline: 2.5609x; 2.5609x over previous
//
#include <hip/hip_runtime.h>
#include <hip/hip_fp16.h>

#define NNODES 100000
#define NEDGES 3200000
#define NGRAPH 4096
#define SBCNT 196         // super-buckets: dst>>9 (512 nodes each)
#define SBCAP 17504       // per-SB capacity: mean 16327 + 9 sigma
#define P1CHUNK 4096
#define P1CAP 56          // LDS bin capacity: mean 20.9 + 7.7 sigma
#define P1GRID 782        // ceil(E / P1CHUNK)
#define AGG_GRID 2048     // exactly 8 blocks/CU on 256 CUs
#define BN_EPS 1e-5f
#define INV_N (1.0f / 100000.0f)

// ---------------- zero helpers ----------------
__global__ void k_zero_i(int* __restrict__ p, int n) {
  int i = blockIdx.x * blockDim.x + threadIdx.x;
  int st = gridDim.x * blockDim.x;
  for (; i < n; i += st) p[i] = 0;
}
__global__ void k_zero_f(float* __restrict__ p, int n) {
  int i = blockIdx.x * blockDim.x + threadIdx.x;
  int st = gridDim.x * blockDim.x;
  for (; i < n; i += st) p[i] = 0.0f;
}

// ---------------- pass 1: LDS-binned partition into 196 super-buckets ----------
__global__ void k_part1(const int* __restrict__ src, const int* __restrict__ dst,
                        int* __restrict__ sbcur, int* __restrict__ sbbuf, int e) {
  __shared__ int cnt[SBCNT];
  __shared__ int base[SBCNT];
  __shared__ int bins[SBCNT * P1CAP];
  int t = threadIdx.x;
  int start = blockIdx.x * P1CHUNK;
  int end = min(start + P1CHUNK, e);
  for (int i = t; i < SBCNT; i += 256) cnt[i] = 0;
  __syncthreads();
  for (int i = start + t; i < end; i += 256) {
    int s = src[i], d = dst[i];
    int sb = d >> 9;
    int en = (s << 9) | (d & 511);
    int pos = atomicAdd(&cnt[sb], 1);
    if (pos < P1CAP) {
      bins[sb * P1CAP + pos] = en;
    } else {  // rare overflow: direct global append (correctness preserved)
      int gp = atomicAdd(&sbcur[sb], 1);
      if (gp < SBCAP) sbbuf[(size_t)sb * SBCAP + gp] = en;
    }
  }
  __syncthreads();
  if (t < SBCNT) {
    int c = min(cnt[t], P1CAP);
    base[t] = (c > 0) ? atomicAdd(&sbcur[t], c) : 0;
  }
  __syncthreads();
  int lane = t & 63, wid = t >> 6;
  for (int b = wid; b < SBCNT; b += 4) {
    int c = min(cnt[b], P1CAP);
    if (lane < c) {
      int gp = base[b] + lane;
      if (gp < SBCAP) sbbuf[(size_t)b * SBCAP + gp] = bins[b * P1CAP + lane];
    }
  }
}

// ---------------- pass 2: single-writer CSR build per super-bucket + dinv ------
__global__ void k_part2(const int* __restrict__ sbcur, const int* __restrict__ sbbuf,
                        int* __restrict__ slots, int* __restrict__ deg,
                        int* __restrict__ rowstart, float* __restrict__ dinv) {
  __shared__ int cnt[512];
  __shared__ int pfx[512];
  __shared__ int cur[512];
  int sb = blockIdx.x;
  int t = threadIdx.x;
  int n = min(sbcur[sb], SBCAP);
  const int* __restrict__ pb = sbbuf + (size_t)sb * SBCAP;
  cnt[t] = 0;
  __syncthreads();
  for (int i = t; i < n; i += 512) atomicAdd(&cnt[pb[i] & 511], 1);
  __syncthreads();
  int myc = cnt[t];
  pfx[t] = myc;
  __syncthreads();
  for (int o = 1; o < 512; o <<= 1) {
    int x = (t >= o) ? pfx[t - o] : 0;
    __syncthreads();
    pfx[t] += x;
    __syncthreads();
  }
  int excl = pfx[t] - myc;
  int node = sb * 512 + t;
  if (node < NNODES) {
    deg[node] = myc;
    rowstart[node] = sb * SBCAP + excl;
    dinv[node] = rsqrtf((float)myc + 1.0f);
  }
  cur[t] = 0;
  __syncthreads();
  pfx[t] = excl;
  __syncthreads();
  for (int i = t; i < n; i += 512) {
    int e = pb[i];
    int dl = e & 511;
    int pos = atomicAdd(&cur[dl], 1);
    slots[(size_t)sb * SBCAP + pfx[dl] + pos] = e >> 9;
  }
}

// ---------------- [n,64] x [64,64] GEMM: k-outer, 16 accs, fp16 I/O ------------
// PRO: 0 = none, 1 = BN+relu on A, 2 = BN+relu+residual on A
// A_HALF: A (and res) are fp16; staging converts to f32 in LDS.
// EPI_DINV: scale row by dinv[row].  EPI_BR: bias + relu (proj layer).
// Output C is always fp16.
template <int PRO, bool A_HALF, bool EPI_DINV, bool EPI_BR>
__global__ void k_gemm64(const void* __restrict__ Ain, const float* __restrict__ W,
                         const float* __restrict__ bias, const float* __restrict__ stats,
                         const float* __restrict__ g, const float* __restrict__ bb,
                         const __half* __restrict__ res, const float* __restrict__ dinv,
                         __half* __restrict__ C, int n) {
  __shared__ float Ws[64 * 64];    // [k][c] row-major
  __shared__ float As[64 * 64];    // [r][k] contiguous
  __shared__ float scs[64], shs[64], bs[64];
  int t = threadIdx.x;
  {
    const float4* W4 = (const float4*)W;
    float4* Ws4 = (float4*)Ws;
    for (int i = t; i < 1024; i += 256) Ws4[i] = W4[i];
  }
  if (t < 64) {
    if (EPI_BR) bs[t] = bias[t];
    if (PRO >= 1) {
      float mu = stats[t] * INV_N;
      float var = stats[64 + t] * INV_N - mu * mu;
      float sc = g[t] * rsqrtf(var + BN_EPS);
      scs[t] = sc;
      shs[t] = bb[t] - mu * sc;
    }
  }
  int row0 = blockIdx.x * 64;
  int rows = min(64, n - row0);
  __syncthreads();
  if constexpr (A_HALF) {
    const __half2* A2 = (const __half2*)((const __half*)Ain + (size_t)row0 * 64);
    const __half2* R2 = (PRO == 2) ? (const __half2*)(res + (size_t)row0 * 64) : nullptr;
    for (int i = t; i < rows * 32; i += 256) {
      float2 f = __half22float2(A2[i]);
      int r = i >> 5;
      int c0 = (i & 31) * 2;
      if (PRO >= 1) {
        f.x = fmaxf(fmaf(f.x, scs[c0], shs[c0]), 0.0f);
        f.y = fmaxf(fmaf(f.y, scs[c0 + 1], shs[c0 + 1]), 0.0f);
        if (PRO == 2) {
          float2 r2 = __half22float2(R2[i]);
          f.x += r2.x;
          f.y += r2.y;
        }
      }
      As[r * 64 + c0] = f.x;
      As[r * 64 + c0 + 1] = f.y;
    }
  } else {
    const float4* A4 = (const float4*)((const float*)Ain + (size_t)row0 * 64);
    float4* As4 = (float4*)As;
    for (int i = t; i < rows * 16; i += 256) As4[i] = A4[i];
  }
  __syncthreads();
  int c = t & 63;
  int w = t >> 6;
  float acc[16];
#pragma unroll
  for (int j = 0; j < 16; ++j) acc[j] = 0.0f;
#pragma unroll 4
  for (int k = 0; k < 64; ++k) {
    float wv = Ws[(k << 6) + c];
#pragma unroll
    for (int j = 0; j < 16; ++j) {
      acc[j] = fmaf(As[((w + 4 * j) << 6) + k], wv, acc[j]);
    }
  }
#pragma unroll
  for (int j = 0; j < 16; ++j) {
    int r = w + 4 * j;
    if (r < rows) {
      float o = acc[j];
      if (EPI_BR) o = fmaxf(o + bs[c], 0.0f);
      if (EPI_DINV) o *= dinv[row0 + r];
      C[(size_t)(row0 + r) * 64 + c] = __float2half(o);
    }
  }
}

// ---------------- aggregate: wave/node; scalar CSR index loads; fp16 gather ----
// 24-deep main chunk + 8/4/1 tails (round-16 proven: 56.5 us, 41% HBM, 70% occ)
__global__ __launch_bounds__(256, 8)
void k_agg(const int* __restrict__ deg, const int* __restrict__ rowstart,
           const int* __restrict__ slots, const __half* __restrict__ y,
           const float* __restrict__ dinv, __half* __restrict__ ag,
           float* __restrict__ pstats) {
  int t = threadIdx.x;
  int lane = t & 63, wid = t >> 6;
  int wave = blockIdx.x * 4 + wid;
  int nw = gridDim.x * 4;
  float s = 0.0f, q = 0.0f;
  for (int node0 = wave; node0 < NNODES; node0 += nw) {
    int node = __builtin_amdgcn_readfirstlane(node0);
    int m = deg[node];
    const int* __restrict__ sp = slots + rowstart[node];
    float a0 = __half2float(y[(size_t)node * 64 + lane]);  // self-loop term
    float a1 = 0.0f, a2 = 0.0f, a3 = 0.0f;
    float a4 = 0.0f, a5 = 0.0f, a6 = 0.0f, a7 = 0.0f;
    int k = 0;
    for (; k + 24 <= m; k += 24) {
      int i00 = sp[k + 0],  i01 = sp[k + 1],  i02 = sp[k + 2],  i03 = sp[k + 3];
      int i04 = sp[k + 4],  i05 = sp[k + 5],  i06 = sp[k + 6],  i07 = sp[k + 7];
      int i08 = sp[k + 8],  i09 = sp[k + 9],  i10 = sp[k + 10], i11 = sp[k + 11];
      int i12 = sp[k + 12], i13 = sp[k + 13], i14 = sp[k + 14], i15 = sp[k + 15];
      int i16 = sp[k + 16], i17 = sp[k + 17], i18 = sp[k + 18], i19 = sp[k + 19];
      int i20 = sp[k + 20], i21 = sp[k + 21], i22 = sp[k + 22], i23 = sp[k + 23];
      __half v00 = y[(size_t)i00 * 64 + lane];
      __half v01 = y[(size_t)i01 * 64 + lane];
      __half v02 = y[(size_t)i02 * 64 + lane];
      __half v03 = y[(size_t)i03 * 64 + lane];
      __half v04 = y[(size_t)i04 * 64 + lane];
      __half v05 = y[(size_t)i05 * 64 + lane];
      __half v06 = y[(size_t)i06 * 64 + lane];
      __half v07 = y[(size_t)i07 * 64 + lane];
      __half v08 = y[(size_t)i08 * 64 + lane];
      __half v09 = y[(size_t)i09 * 64 + lane];
      __half v10 = y[(size_t)i10 * 64 + lane];
      __half v11 = y[(size_t)i11 * 64 + lane];
      __half v12 = y[(size_t)i12 * 64 + lane];
      __half v13 = y[(size_t)i13 * 64 + lane];
      __half v14 = y[(size_t)i14 * 64 + lane];
      __half v15 = y[(size_t)i15 * 64 + lane];
      __half v16 = y[(size_t)i16 * 64 + lane];
      __half v17 = y[(size_t)i17 * 64 + lane];
      __half v18 = y[(size_t)i18 * 64 + lane];
      __half v19 = y[(size_t)i19 * 64 + lane];
      __half v20 = y[(size_t)i20 * 64 + lane];
      __half v21 = y[(size_t)i21 * 64 + lane];
      __half v22 = y[(size_t)i22 * 64 + lane];
      __half v23 = y[(size_t)i23 * 64 + lane];
      a0 += __half2float(v00); a1 += __half2float(v01);
      a2 += __half2float(v02); a3 += __half2float(v03);
      a4 += __half2float(v04); a5 += __half2float(v05);
      a6 += __half2float(v06); a7 += __half2float(v07);
      a0 += __half2float(v08); a1 += __half2float(v09);
      a2 += __half2float(v10); a3 += __half2float(v11);
      a4 += __half2float(v12); a5 += __half2float(v13);
      a6 += __half2float(v14); a7 += __half2float(v15);
      a0 += __half2float(v16); a1 += __half2float(v17);
      a2 += __half2float(v18); a3 += __half2float(v19);
      a4 += __half2float(v20); a5 += __half2float(v21);
      a6 += __half2float(v22); a7 += __half2float(v23);
    }
    for (; k + 8 <= m; k += 8) {
      int i0 = sp[k + 0], i1 = sp[k + 1], i2 = sp[k + 2], i3 = sp[k + 3];
      int i4 = sp[k + 4], i5 = sp[k + 5], i6 = sp[k + 6], i7 = sp[k + 7];
      __half v0 = y[(size_t)i0 * 64 + lane];
      __half v1 = y[(size_t)i1 * 64 + lane];
      __half v2 = y[(size_t)i2 * 64 + lane];
      __half v3 = y[(size_t)i3 * 64 + lane];
      __half v4 = y[(size_t)i4 * 64 + lane];
      __half v5 = y[(size_t)i5 * 64 + lane];
      __half v6 = y[(size_t)i6 * 64 + lane];
      __half v7 = y[(size_t)i7 * 64 + lane];
      a0 += __half2float(v0); a1 += __half2float(v1);
      a2 += __half2float(v2); a3 += __half2float(v3);
      a4 += __half2float(v4); a5 += __half2float(v5);
      a6 += __half2float(v6); a7 += __half2float(v7);
    }
    for (; k + 4 <= m; k += 4) {
      int i0 = sp[k + 0], i1 = sp[k + 1], i2 = sp[k + 2], i3 = sp[k + 3];
      __half v0 = y[(size_t)i0 * 64 + lane];
      __half v1 = y[(size_t)i1 * 64 + lane];
      __half v2 = y[(size_t)i2 * 64 + lane];
      __half v3 = y[(size_t)i3 * 64 + lane];
      a0 += __half2float(v0); a1 += __half2float(v1);
      a2 += __half2float(v2); a3 += __half2float(v3);
    }
    for (; k < m; ++k) a0 += __half2float(y[(size_t)sp[k] * 64 + lane]);
    float o = dinv[node] * (((a0 + a1) + (a2 + a3)) + ((a4 + a5) + (a6 + a7)));
    ag[(size_t)node0 * 64 + lane] = __float2half(o);
    s += o;
    q = fmaf(o, o, q);
  }
  __shared__ float ls[256], lq[256];
  ls[t] = s;
  lq[t] = q;
  __syncthreads();
  if (t < 64) {
    pstats[blockIdx.x * 128 + t] = ls[t] + ls[64 + t] + ls[128 + t] + ls[192 + t];
    pstats[blockIdx.x * 128 + 64 + t] = lq[t] + lq[64 + t] + lq[128 + t] + lq[192 + t];
  }
}

// ---------------- reduce pstats[AGG_GRID][128] -> stats[128] ----------------
__global__ void k_stats_reduce(const float* __restrict__ pstats, float* __restrict__ stats) {
  __shared__ float red[256];
  int c = blockIdx.x;  // channel 0..127
  int t = threadIdx.x;
  float s = 0.0f;
  for (int i = t; i < AGG_GRID; i += 256) s += pstats[i * 128 + c];
  red[t] = s;
  __syncthreads();
  for (int o = 128; o >= 1; o >>= 1) {
    if (t < o) red[t] += red[t + o];
    __syncthreads();
  }
  if (t == 0) stats[c] = red[0];
}

// ---------------- pool: run-length accumulate over sorted batch, fused BN3+relu ----
__global__ void k_pool(const __half* __restrict__ ag, const float* __restrict__ stats,
                       const float* __restrict__ g, const float* __restrict__ bb,
                       const int* __restrict__ batch, float* __restrict__ psum,
                       float* __restrict__ pcnt) {
  int t = threadIdx.x, lane = t & 63;
  int wave = blockIdx.x * 4 + (t >> 6);
  int c0 = wave * 32;
  if (c0 >= NNODES) return;
  float mu = stats[lane] * INV_N;
  float var = stats[64 + lane] * INV_N - mu * mu;
  float sc = g[lane] * rsqrtf(var + BN_EPS);
  float sh = bb[lane] - mu * sc;
  int gprev = -1;
  float av = 0.0f, cv = 0.0f;
  int end = min(c0 + 32, NNODES);
  for (int node = c0; node < end; ++node) {
    int gi = batch[node];
    if (gi != gprev) {
      if (gprev >= 0) {
        atomicAdd(&psum[gprev * 64 + lane], av);
        if (lane == 0) atomicAdd(&pcnt[gprev], cv);
      }
      gprev = gi;
      av = 0.0f;
      cv = 0.0f;
    }
    av += fmaxf(fmaf(__half2float(ag[(size_t)node * 64 + lane]), sc, sh), 0.0f);
    cv += 1.0f;
  }
  if (gprev >= 0) {
    atomicAdd(&psum[gprev * 64 + lane], av);
    if (lane == 0) atomicAdd(&pcnt[gprev], cv);
  }
}

// ---------------- head MLP ----------------
__global__ void k_head(const float* __restrict__ psum, const float* __restrict__ pcnt,
                       const float* __restrict__ W1, const float* __restrict__ b1,
                       const float* __restrict__ W2, const float* __restrict__ b2,
                       float* __restrict__ out) {
  int gidx = blockIdx.x;
  int t = threadIdx.x;
  __shared__ float pooled[64];
  __shared__ float hid[32];
  float cnt = fmaxf(pcnt[gidx], 1.0f);
  pooled[t] = psum[gidx * 64 + t] / cnt;
  __syncthreads();
  if (t < 32) {
    float a = b1[t];
#pragma unroll
    for (int k = 0; k < 64; ++k) a = fmaf(pooled[k], W1[k * 32 + t], a);
    hid[t] = fmaxf(a, 0.0f);
  }
  __syncthreads();
  if (t == 0) {
    float o = b2[0];
#pragma unroll
    for (int j = 0; j < 32; ++j) o = fmaf(hid[j], W2[j], o);
    out[gidx] = o;
  }
}

extern "C" void kernel_launch(void* const* d_in, const int* in_sizes, int n_in,
                              void* d_out, int out_size, void* d_ws, size_t ws_size,
                              hipStream_t stream) {
  const float* x       = (const float*)d_in[0];
  const int*   eidx    = (const int*)d_in[1];
  const int*   batch   = (const int*)d_in[2];
  const float* proj_W  = (const float*)d_in[3];
  const float* proj_b  = (const float*)d_in[4];
  const float* conv1_W = (const float*)d_in[5];
  const float* conv2_W = (const float*)d_in[7];
  const float* conv3_W = (const float*)d_in[9];
  const float* bn1_g   = (const float*)d_in[11];
  const float* bn1_b   = (const float*)d_in[12];
  const float* bn2_g   = (const float*)d_in[13];
  const float* bn2_b   = (const float*)d_in[14];
  const float* bn3_g   = (const float*)d_in[15];
  const float* bn3_b   = (const float*)d_in[16];
  const float* head_W1 = (const float*)d_in[17];
  const float* head_b1 = (const float*)d_in[18];
  const float* head_W2 = (const float*)d_in[19];
  const float* head_b2 = (const float*)d_in[20];
  float* out = (float*)d_out;

  const int N = NNODES, E = NEDGES, G = NGRAPH;
  const int* src = eidx;
  const int* dst = eidx + E;

  char* p = (char*)d_ws;
  auto align256 = [](size_t v) { return (v + 255) & ~(size_t)255; };
  int* sbcur = (int*)p;       p += align256((size_t)SBCNT * 4);
  int* deg = (int*)p;         p += align256((size_t)N * 4);
  int* rowstart = (int*)p;    p += align256((size_t)N * 4);
  int* slots = (int*)p;       p += align256((size_t)SBCNT * SBCAP * 4);  // 13.7 MB CSR
  float* dinv = (float*)p;    p += align256((size_t)N * 4);
  __half* x016 = (__half*)p;  p += align256((size_t)N * 64 * 2);  // 12.8 MB
  __half* y16 = (__half*)p;   p += align256((size_t)N * 64 * 2);  // 12.8 MB
  __half* ag16 = (__half*)p;  p += align256((size_t)N * 64 * 2);  // 12.8 MB
  float* pstats = (float*)p;  p += align256((size_t)AGG_GRID * 128 * 4);
  float* stats1 = (float*)p;  p += align256(128 * 4);
  float* stats2 = (float*)p;  p += align256(128 * 4);
  float* stats3 = (float*)p;  p += align256(128 * 4);
  float* psum = (float*)p;    p += align256((size_t)G * 64 * 4);
  float* pcnt = (float*)p;    p += align256((size_t)G * 4);
  // sbbuf (13.7 MB) aliases y16+ag16 (25.6 MB): dead before either is written.
  int* sbbuf = (int*)y16;

  const int TB = 256;
  int gemm_grid = (N + 63) / 64;

  // ---- adjacency build: LDS-binned partition + single-writer CSR (+dinv) ----
  k_zero_i<<<1, SBCNT, 0, stream>>>(sbcur, SBCNT);
  k_part1<<<P1GRID, TB, 0, stream>>>(src, dst, sbcur, sbbuf, E);
  k_part2<<<SBCNT, 512, 0, stream>>>(sbcur, sbbuf, slots, deg, rowstart, dinv);

  // zero pool buffers
  k_zero_f<<<(G * 64 + G + TB - 1) / TB, TB, 0, stream>>>(psum, G * 64 + G);

  // ---- proj: x0 = relu(x @ W + b)  (f32 in, fp16 out) ----
  k_gemm64<0, false, false, true><<<gemm_grid, TB, 0, stream>>>(
      x, proj_W, proj_b, nullptr, nullptr, nullptr, nullptr, nullptr, x016, N);

  // ---- layer 1 ----
  k_gemm64<0, true, true, false><<<gemm_grid, TB, 0, stream>>>(
      x016, conv1_W, nullptr, nullptr, nullptr, nullptr, nullptr, dinv, y16, N);
  k_agg<<<AGG_GRID, TB, 0, stream>>>(deg, rowstart, slots, y16, dinv, ag16, pstats);
  k_stats_reduce<<<128, TB, 0, stream>>>(pstats, stats1);

  // ---- layer 2 (BN1+relu fused into A-load) ----
  k_gemm64<1, true, true, false><<<gemm_grid, TB, 0, stream>>>(
      ag16, conv2_W, nullptr, stats1, bn1_g, bn1_b, nullptr, dinv, y16, N);
  k_agg<<<AGG_GRID, TB, 0, stream>>>(deg, rowstart, slots, y16, dinv, ag16, pstats);
  k_stats_reduce<<<128, TB, 0, stream>>>(pstats, stats2);

  // ---- layer 3 (BN2+relu+x0 residual fused into A-load) ----
  k_gemm64<2, true, true, false><<<gemm_grid, TB, 0, stream>>>(
      ag16, conv3_W, nullptr, stats2, bn2_g, bn2_b, x016, dinv, y16, N);
  k_agg<<<AGG_GRID, TB, 0, stream>>>(deg, rowstart, slots, y16, dinv, ag16, pstats);
  k_stats_reduce<<<128, TB, 0, stream>>>(pstats, stats3);

  // ---- pool (BN3+relu fused, run-length over sorted batch) + head ----
  k_pool<<<(N + 127) / 128, TB, 0, stream>>>(ag16, stats3, bn3_g, bn3_b, batch, psum, pcnt);
  k_head<<<G, 64, 0, stream>>>(psum, pcnt, head_W1, head_b1, head_W2, head_b2, out);
}